// Round 10
// baseline (251.401 us; speedup 1.0000x reference)
//
#include <hip/hip_runtime.h>
#include <cmath>

#define B_ 64
#define N_ 19
#define SEG_ 15
#define T_ 400
#define FIN_ 64
#define HID_ 128
#define K_ 4
#define NH_ 4
#define DM_ 64
#define FF_ 128
#define L_ 4
#define NC_ 3
#define EPS_ 1e-5f

typedef __attribute__((ext_vector_type(8))) short bf16x8;
typedef __attribute__((ext_vector_type(4))) short bf16x4;
typedef __attribute__((ext_vector_type(4))) float f32x4;
typedef unsigned short ushort_t;

__device__ __forceinline__ ushort_t f2bf(float x) {
  union { float f; unsigned u; } a; a.f = x;
  unsigned r = a.u + 0x7fffu + ((a.u >> 16) & 1u);
  return (ushort_t)(r >> 16);
}
__device__ __forceinline__ float bf2f(ushort_t h) {
  union { unsigned u; float f; } a; a.u = ((unsigned)h) << 16;
  return a.f;
}
#define MFMA(a, b, c) __builtin_amdgcn_mfma_f32_16x16x32_bf16((a), (b), (c), 0, 0, 0)

// ================= k_prep =================
__global__ __launch_bounds__(256) void k_prep(
    const float* __restrict__ c1w, const float* __restrict__ c2w,
    const float* __restrict__ wqkv, const float* __restrict__ wo,
    const float* __restrict__ w1, const float* __restrict__ w2,
    const float* __restrict__ g1W, const float* __restrict__ g2W,
    ushort_t* __restrict__ bt,
    ushort_t* __restrict__ Th, ushort_t* __restrict__ Tl,
    ushort_t* __restrict__ W1h, ushort_t* __restrict__ W1l,
    ushort_t* __restrict__ W2h, ushort_t* __restrict__ W2l,
    ushort_t* __restrict__ C1h, ushort_t* __restrict__ C1l) {
  int gid = blockIdx.x * 256 + threadIdx.x;
  if (gid < 18944) {
    int oc = gid / 296, k = gid - oc * 296;
    int ic = k & 31, kk = k >> 5;
    ushort_t v = 0;
    if (kk < 9) v = f2bf(c2w[oc * 288 + ic * 9 + kk]);
    bt[gid] = v;
  } else if (gid < 68096) {
    int i = gid - 18944;
    int l = i / 12288, r = i % 12288;
    float v = wqkv[i];
    ushort_t h = f2bf(v);
    int dst = l * 32768 + r;
    Th[dst] = h; Tl[dst] = f2bf(v - bf2f(h));
  } else if (gid < 84480) {
    int i = gid - 68096;
    int l = i / 4096, r = i % 4096;
    float v = wo[i];
    ushort_t h = f2bf(v);
    int dst = l * 32768 + 12288 + r;
    Th[dst] = h; Tl[dst] = f2bf(v - bf2f(h));
  } else if (gid < 117248) {
    int i = gid - 84480;
    int l = i / 8192, r = i % 8192;
    float v = w1[i];
    ushort_t h = f2bf(v);
    int dst = l * 32768 + 16384 + r;
    Th[dst] = h; Tl[dst] = f2bf(v - bf2f(h));
  } else if (gid < 150016) {
    int i = gid - 117248;
    int l = i / 8192, r = i % 8192;
    float v = w2[i];
    ushort_t h = f2bf(v);
    int dst = l * 32768 + 24576 + r;
    Th[dst] = h; Tl[dst] = f2bf(v - bf2f(h));
  } else if (gid < 158208) {
    int i = gid - 150016;
    float v = g1W[i];
    ushort_t h = f2bf(v);
    W1h[i] = h;
    W1l[i] = f2bf(v - bf2f(h));
  } else if (gid < 166400) {
    int i = gid - 158208;
    float v = g2W[i];
    ushort_t h = f2bf(v);
    W2h[i] = h;
    W2l[i] = f2bf(v - bf2f(h));
  } else if (gid < 167424) {
    int i = gid - 166400;
    int oc = i >> 5, kk = i & 31;
    float v = (kk < 25) ? c1w[oc * 25 + kk] : 0.f;
    ushort_t h = f2bf(v);
    C1h[i] = h;
    C1l[i] = f2bf(v - bf2f(h));
  }
}

// ================= Kernel 1: temporal encoder (unchanged) ==========
#define RPB 4
#define ICP 40
#define P1R 40
#define OFF_XPH 0
#define OFF_XPL 3840
#define OFF_P1  7680
#define SMEM_T  20480

__global__ __launch_bounds__(256, 4) void k_temporal(
    const float* __restrict__ X, const float* __restrict__ c1b,
    const float* __restrict__ c2b,
    const ushort_t* __restrict__ C1h, const ushort_t* __restrict__ C1l,
    const ushort_t* __restrict__ BmatT, float* __restrict__ Xf) {
  __shared__ __align__(16) unsigned char smem[SMEM_T];
  ushort_t* xph = (ushort_t*)(smem + OFF_XPH);
  ushort_t* xpl = (ushort_t*)(smem + OFF_XPL);
  ushort_t* p1T = (ushort_t*)(smem + OFF_P1);
  float* Dbuf = (float*)smem;

  const int tid = threadIdx.x;
  const int row0 = blockIdx.x * RPB;
  const int lane = tid & 63, wv = tid >> 6;
  const int quad = lane >> 4, nl = lane & 15;

  for (int i = tid; i < 3200; i += 256) ((unsigned*)p1T)[i] = 0u;
  for (int r = 0; r < RPB; ++r) {
    const int gr = row0 + r;
    const int n = gr % N_;
    const int s = (gr / N_) % SEG_;
    const int b = gr / (N_ * SEG_);
    const float* xin = X + (((size_t)b * N_ + n) * SEG_ + s) * T_ - 12;
    for (int i = tid; i < 480; i += 256) {
      float v = (i >= 12 && i < 412) ? xin[i] : 0.f;
      ushort_t h = f2bf(v);
      xph[r * 480 + i] = h;
      xpl[r * 480 + i] = f2bf(v - bf2f(h));
    }
  }
  __syncthreads();

  {
    bf16x8 bh0 = *(const bf16x8*)(C1h + nl * 32 + quad * 8);
    bf16x8 bh1 = *(const bf16x8*)(C1h + (16 + nl) * 32 + quad * 8);
    bf16x8 bl0 = *(const bf16x8*)(C1l + nl * 32 + quad * 8);
    bf16x8 bl1 = *(const bf16x8*)(C1l + (16 + nl) * 32 + quad * 8);
    const float bias0 = c1b[nl], bias1 = c1b[16 + nl];
    for (int t = wv; t < 28; t += 4) {
      const int r = t / 7, mt = t - r * 7;
      const int aoff = r * 480 + mt * 64 + nl * 4 + quad * 8;
      union { bf16x4 q[2]; bf16x8 v; } ah, al;
      ah.q[0] = *(const bf16x4*)(xph + aoff);
      ah.q[1] = *(const bf16x4*)(xph + aoff + 4);
      al.q[0] = *(const bf16x4*)(xpl + aoff);
      al.q[1] = *(const bf16x4*)(xpl + aoff + 4);
      f32x4 a0 = (f32x4){0.f, 0.f, 0.f, 0.f};
      a0 = MFMA(ah.v, bh0, a0);
      a0 = MFMA(al.v, bh0, a0);
      a0 = MFMA(ah.v, bl0, a0);
      f32x4 a1 = (f32x4){0.f, 0.f, 0.f, 0.f};
      a1 = MFMA(ah.v, bh1, a1);
      a1 = MFMA(al.v, bh1, a1);
      a1 = MFMA(ah.v, bl1, a1);
      const int j = mt * 4 + quad;
      if (j < 25) {
        float m0 = fmaxf(fmaxf(a0[0], a0[1]), fmaxf(a0[2], a0[3]));
        float m1 = fmaxf(fmaxf(a1[0], a1[1]), fmaxf(a1[2], a1[3]));
        p1T[(r * P1R + j + 4) * ICP + nl] = f2bf(fmaxf(m0 + bias0, 0.f));
        p1T[(r * P1R + j + 4) * ICP + 16 + nl] = f2bf(fmaxf(m1 + bias1, 0.f));
      }
    }
  }
  __syncthreads();

  f32x4 acc[4];
  int abase[4];
#pragma unroll
  for (int tm = 0; tm < 4; ++tm) {
    acc[tm] = (f32x4){0.f, 0.f, 0.f, 0.f};
    int m = tm * 16 + nl;
    int rl = m / 14;
    int op = m - rl * 14;
    if (rl > 3) rl = 3;
    if (op > 13) op = 13;
    abase[tm] = (rl * P1R + 2 * op) * ICP + quad * 8;
  }
  const ushort_t* brow = BmatT + (wv * 16 + nl) * 296 + quad * 8;
#pragma unroll
  for (int kk = 0; kk < 9; ++kk) {
    bf16x8 bfr = *(const bf16x8*)(brow + kk * 32);
#pragma unroll
    for (int tm = 0; tm < 4; ++tm) {
      bf16x8 afr = *(const bf16x8*)(p1T + abase[tm] + kk * ICP);
      acc[tm] = MFMA(afr, bfr, acc[tm]);
    }
  }
  __syncthreads();

#pragma unroll
  for (int tm = 0; tm < 4; ++tm)
#pragma unroll
    for (int rg = 0; rg < 4; ++rg)
      Dbuf[(tm * 16 + quad * 4 + rg) * 66 + wv * 16 + nl] = acc[tm][rg];
  __syncthreads();

  for (int o = tid; o < RPB * 64; o += 256) {
    int rl = o >> 6, oc = o & 63;
    float bias = c2b[oc];
    const float* dr = Dbuf + (rl * 14) * 66 + oc;
    float s = 0.f;
#pragma unroll
    for (int jj = 0; jj < 6; ++jj) {
      float v = fmaxf(dr[(2 * jj) * 66], dr[(2 * jj + 1) * 66]) + bias;
      s += fmaxf(v, 0.f);
    }
    Xf[(size_t)(row0 + rl) * FIN_ + oc] = s * (1.f / 6.f);
  }
}

// ================= Kernel 2: fused GCN, all-MFMA (unchanged) =============
__global__ __launch_bounds__(256, 2) void k_gcn(
    const float* __restrict__ A, const float* __restrict__ Xf,
    const ushort_t* __restrict__ W1h, const ushort_t* __restrict__ W1l,
    const ushort_t* __restrict__ W2h, const ushort_t* __restrict__ W2l,
    const float* __restrict__ q1, const float* __restrict__ q2,
    const float* __restrict__ b1g, const float* __restrict__ b1b,
    const float* __restrict__ b1m, const float* __restrict__ b1v,
    const float* __restrict__ b2g, const float* __restrict__ b2b,
    const float* __restrict__ b2m, const float* __restrict__ b2v,
    float* __restrict__ G) {
  const int bs = blockIdx.x;
  const int b = bs / SEG_;
  const int s = bs % SEG_;
  const int tid = threadIdx.x;
  const int lane = tid & 63, wv = tid >> 6;
  const int quad = lane >> 4, nl = lane & 15;

  __shared__ __align__(16) ushort_t xh[32 * 72], xl[32 * 72];
  __shared__ __align__(16) ushort_t Hh[32 * 136], Hl[32 * 136];
  __shared__ __align__(16) ushort_t a1h[32 * 40], a1l[32 * 40];
  __shared__ __align__(16) ushort_t a2h[32 * 40], a2l[32 * 40];
  __shared__ __align__(16) ushort_t yTh[128 * 40], yTl[128 * 40];
  __shared__ float zbuf[N_ * 64];
  __shared__ float sc1[HID_], sh1[HID_], sc2[FIN_], sh2[FIN_];

  for (int i = tid; i < 32 * 72 / 2; i += 256) {
    ((unsigned*)xh)[i] = 0u; ((unsigned*)xl)[i] = 0u;
  }
  for (int i = tid; i < 32 * 136 / 2; i += 256) {
    ((unsigned*)Hh)[i] = 0u; ((unsigned*)Hl)[i] = 0u;
  }
  for (int i = tid; i < 32 * 40 / 2; i += 256) {
    ((unsigned*)a1h)[i] = 0u; ((unsigned*)a1l)[i] = 0u;
    ((unsigned*)a2h)[i] = 0u; ((unsigned*)a2l)[i] = 0u;
  }
  for (int o = tid; o < HID_; o += 256) {
    float sc = b1g[o] * rsqrtf(b1v[o] + EPS_);
    sc1[o] = sc; sh1[o] = b1b[o] - b1m[o] * sc;
  }
  for (int o = tid; o < FIN_; o += 256) {
    float sc = b2g[o] * rsqrtf(b2v[o] + EPS_);
    sc2[o] = sc; sh2[o] = b2b[o] - b2m[o] * sc;
  }
  __syncthreads();

  {
    float p0 = q1[0], p1 = q1[1], p2 = q1[2], p3 = q1[3];
    float mx = fmaxf(fmaxf(p0, p1), fmaxf(p2, p3));
    float e0 = expf(p0 - mx), e1 = expf(p1 - mx), e2 = expf(p2 - mx), e3 = expf(p3 - mx);
    float inv = 1.f / (e0 + e1 + e2 + e3);
    float a0 = e0 * inv, a1 = e1 * inv, a2 = e2 * inv, a3 = e3 * inv;
    float r0 = q2[0], r1 = q2[1], r2 = q2[2], r3 = q2[3];
    float mx2 = fmaxf(fmaxf(r0, r1), fmaxf(r2, r3));
    float f0 = expf(r0 - mx2), f1 = expf(r1 - mx2), f2 = expf(r2 - mx2), f3 = expf(r3 - mx2);
    float inv2 = 1.f / (f0 + f1 + f2 + f3);
    float c0 = f0 * inv2, c1 = f1 * inv2, c2 = f2 * inv2, c3 = f3 * inv2;
    const size_t kstride = (size_t)SEG_ * N_ * N_;
    const float* Ab = A + ((size_t)b * K_ * SEG_ + s) * (N_ * N_);
    for (int i = tid; i < N_ * N_; i += 256) {
      int n = i / N_, m = i - n * N_;
      float v0 = Ab[i], v1 = Ab[i + kstride], v2 = Ab[i + 2 * kstride], v3 = Ab[i + 3 * kstride];
      float w1v = a0 * v0 + a1 * v1 + a2 * v2 + a3 * v3;
      float w2v = c0 * v0 + c1 * v1 + c2 * v2 + c3 * v3;
      ushort_t h1 = f2bf(w1v);
      a1h[n * 40 + m] = h1; a1l[n * 40 + m] = f2bf(w1v - bf2f(h1));
      ushort_t h2 = f2bf(w2v);
      a2h[n * 40 + m] = h2; a2l[n * 40 + m] = f2bf(w2v - bf2f(h2));
    }
  }
  {
    const float* xb = Xf + (size_t)bs * N_ * FIN_;
    for (int i = tid; i < N_ * FIN_; i += 256) {
      int r = i >> 6, f = i & 63;
      float v = xb[i];
      ushort_t h = f2bf(v);
      xh[r * 72 + f] = h;
      xl[r * 72 + f] = f2bf(v - bf2f(h));
    }
  }
  __syncthreads();

#pragma unroll
  for (int mtl = 0; mtl < 2; ++mtl) {
    const int om = (wv * 2 + mtl) * 16;
#pragma unroll
    for (int nt = 0; nt < 2; ++nt) {
      f32x4 acc = (f32x4){0.f, 0.f, 0.f, 0.f};
#pragma unroll
      for (int ks = 0; ks < 2; ++ks) {
        bf16x8 ah = *(const bf16x8*)(W1h + (om + nl) * 64 + ks * 32 + quad * 8);
        bf16x8 al = *(const bf16x8*)(W1l + (om + nl) * 64 + ks * 32 + quad * 8);
        bf16x8 bh = *(const bf16x8*)(xh + (nt * 16 + nl) * 72 + ks * 32 + quad * 8);
        bf16x8 bl = *(const bf16x8*)(xl + (nt * 16 + nl) * 72 + ks * 32 + quad * 8);
        acc = MFMA(ah, bh, acc);
        acc = MFMA(al, bh, acc);
        acc = MFMA(ah, bl, acc);
      }
#pragma unroll
      for (int r = 0; r < 4; ++r) {
        int o = om + quad * 4 + r, node = nt * 16 + nl;
        float v = acc[r];
        ushort_t hh = f2bf(v);
        yTh[o * 40 + node] = hh;
        yTl[o * 40 + node] = f2bf(v - bf2f(hh));
      }
    }
  }
  __syncthreads();

#pragma unroll
  for (int mt = 0; mt < 2; ++mt) {
#pragma unroll
    for (int ntl = 0; ntl < 2; ++ntl) {
      const int nt = wv * 2 + ntl;
      f32x4 acc = (f32x4){0.f, 0.f, 0.f, 0.f};
      bf16x8 ah = *(const bf16x8*)(a1h + (mt * 16 + nl) * 40 + quad * 8);
      bf16x8 al = *(const bf16x8*)(a1l + (mt * 16 + nl) * 40 + quad * 8);
      bf16x8 bh = *(const bf16x8*)(yTh + (nt * 16 + nl) * 40 + quad * 8);
      bf16x8 bl = *(const bf16x8*)(yTl + (nt * 16 + nl) * 40 + quad * 8);
      acc = MFMA(ah, bh, acc);
      acc = MFMA(al, bh, acc);
      acc = MFMA(ah, bl, acc);
      const int o = nt * 16 + nl;
      const float sc = sc1[o], sh = sh1[o];
#pragma unroll
      for (int r = 0; r < 4; ++r) {
        int node = mt * 16 + quad * 4 + r;
        if (node < N_) {
          float h = fmaxf(acc[r] * sc + sh, 0.f);
          ushort_t hh = f2bf(h);
          Hh[node * 136 + o] = hh;
          Hl[node * 136 + o] = f2bf(h - bf2f(hh));
        }
      }
    }
  }
  __syncthreads();

  {
    const int om = wv * 16;
#pragma unroll
    for (int nt = 0; nt < 2; ++nt) {
      f32x4 acc = (f32x4){0.f, 0.f, 0.f, 0.f};
#pragma unroll
      for (int ks = 0; ks < 4; ++ks) {
        bf16x8 ah = *(const bf16x8*)(W2h + (om + nl) * 128 + ks * 32 + quad * 8);
        bf16x8 al = *(const bf16x8*)(W2l + (om + nl) * 128 + ks * 32 + quad * 8);
        bf16x8 bh = *(const bf16x8*)(Hh + (nt * 16 + nl) * 136 + ks * 32 + quad * 8);
        bf16x8 bl = *(const bf16x8*)(Hl + (nt * 16 + nl) * 136 + ks * 32 + quad * 8);
        acc = MFMA(ah, bh, acc);
        acc = MFMA(al, bh, acc);
        acc = MFMA(ah, bl, acc);
      }
#pragma unroll
      for (int r = 0; r < 4; ++r) {
        int o2 = om + quad * 4 + r, node = nt * 16 + nl;
        float v = acc[r];
        ushort_t hh = f2bf(v);
        yTh[o2 * 40 + node] = hh;
        yTl[o2 * 40 + node] = f2bf(v - bf2f(hh));
      }
    }
  }
  __syncthreads();

#pragma unroll
  for (int mt = 0; mt < 2; ++mt) {
    f32x4 acc = (f32x4){0.f, 0.f, 0.f, 0.f};
    bf16x8 ah = *(const bf16x8*)(a2h + (mt * 16 + nl) * 40 + quad * 8);
    bf16x8 al = *(const bf16x8*)(a2l + (mt * 16 + nl) * 40 + quad * 8);
    bf16x8 bh = *(const bf16x8*)(yTh + (wv * 16 + nl) * 40 + quad * 8);
    bf16x8 bl = *(const bf16x8*)(yTl + (wv * 16 + nl) * 40 + quad * 8);
    acc = MFMA(ah, bh, acc);
    acc = MFMA(al, bh, acc);
    acc = MFMA(ah, bl, acc);
    const int o2 = wv * 16 + nl;
    const float sc = sc2[o2], sh = sh2[o2];
#pragma unroll
    for (int r = 0; r < 4; ++r) {
      int node = mt * 16 + quad * 4 + r;
      if (node < N_)
        zbuf[node * 64 + o2] = fmaxf(acc[r] * sc + sh, 0.f);
    }
  }
  __syncthreads();

  if (tid < FIN_) {
    float ssum = 0.f;
#pragma unroll
    for (int nn = 0; nn < N_; ++nn) ssum += zbuf[nn * 64 + tid];
    G[(size_t)bs * FIN_ + tid] = ssum * (1.f / (float)N_);
  }
}

// ================= Kernel 3: transformer — 1 wave, SW-pipelined weights ===
// Barrier-free; weight loads explicitly register-prefetched so each stage's
// global latency hides under the previous stage's compute.
__global__ __launch_bounds__(64, 1) void k_transformer(
    const float* __restrict__ G, const float* __restrict__ cls,
    const float* __restrict__ pos,
    const ushort_t* __restrict__ Th, const ushort_t* __restrict__ Tl,
    const float* __restrict__ bqkv, const float* __restrict__ bo,
    const float* __restrict__ ln1g, const float* __restrict__ ln1b,
    const float* __restrict__ b1, const float* __restrict__ b2,
    const float* __restrict__ ln2g, const float* __restrict__ ln2b,
    const float* __restrict__ clfw, const float* __restrict__ clfb,
    float* __restrict__ out) {
  const int b = blockIdx.x;
  const int lane = threadIdx.x;
  const int quad = lane >> 4, nl = lane & 15;

  __shared__ float xbuf[16 * 64];
  __shared__ __align__(16) ushort_t xh[16 * 72], xl[16 * 72];
  __shared__ float qkvb[16 * 196];
  __shared__ float scb[16 * 17];
  __shared__ __align__(16) ushort_t oh[16 * 72], ol[16 * 72];
  __shared__ __align__(16) ushort_t h1h[16 * 136], h1l[16 * 136];
  __shared__ float tmpb[16 * 64];

  // ---- entry staging ----
#pragma unroll
  for (int g = 0; g < 4; ++g) {
    const int t = g * 4 + quad;
    float4 base = (t == 0) ? ((const float4*)cls)[nl]
                           : ((const float4*)(G + ((size_t)b * SEG_ + (t - 1)) * DM_))[nl];
    float4 p = ((const float4*)(pos + t * DM_))[nl];
    float4 v;
    v.x = base.x + p.x; v.y = base.y + p.y;
    v.z = base.z + p.z; v.w = base.w + p.w;
    ((float4*)(xbuf + t * 64))[nl] = v;
    const int bi = t * 72 + nl * 4;
    ushort_t h0 = f2bf(v.x), h1 = f2bf(v.y), h2 = f2bf(v.z), h3 = f2bf(v.w);
    xh[bi + 0] = h0; xh[bi + 1] = h1; xh[bi + 2] = h2; xh[bi + 3] = h3;
    xl[bi + 0] = f2bf(v.x - bf2f(h0));
    xl[bi + 1] = f2bf(v.y - bf2f(h1));
    xl[bi + 2] = f2bf(v.z - bf2f(h2));
    xl[bi + 3] = f2bf(v.w - bf2f(h3));
  }

  for (int l = 0; l < L_; ++l) {
    const ushort_t* TH = Th + l * 32768;
    const ushort_t* TL = Tl + l * 32768;

    // ================= qkv: 6 pairs with 1-pair lookahead =================
    {
      float qb[12];
#pragma unroll
      for (int nt = 0; nt < 12; ++nt) qb[nt] = bqkv[l * 192 + nt * 16 + nl];
      bf16x8 xah[2], xal[2];
#pragma unroll
      for (int ks = 0; ks < 2; ++ks) {
        xah[ks] = *(const bf16x8*)(xh + nl * 72 + ks * 32 + quad * 8);
        xal[ks] = *(const bf16x8*)(xl + nl * 72 + ks * 32 + quad * 8);
      }
      bf16x8 wh[2][2][2], wl[2][2][2];
#pragma unroll
      for (int tp = 0; tp < 2; ++tp)
#pragma unroll
        for (int ks = 0; ks < 2; ++ks) {
          wh[0][tp][ks] = *(const bf16x8*)(TH + (tp * 16 + nl) * 64 + ks * 32 + quad * 8);
          wl[0][tp][ks] = *(const bf16x8*)(TL + (tp * 16 + nl) * 64 + ks * 32 + quad * 8);
        }
#pragma unroll
      for (int pr = 0; pr < 6; ++pr) {
        const int cb = pr & 1, nb = cb ^ 1;
        if (pr < 5) {
#pragma unroll
          for (int tp = 0; tp < 2; ++tp)
#pragma unroll
            for (int ks = 0; ks < 2; ++ks) {
              const int nt = (pr + 1) * 2 + tp;
              wh[nb][tp][ks] = *(const bf16x8*)(TH + (nt * 16 + nl) * 64 + ks * 32 + quad * 8);
              wl[nb][tp][ks] = *(const bf16x8*)(TL + (nt * 16 + nl) * 64 + ks * 32 + quad * 8);
            }
        }
        f32x4 a0 = (f32x4){0.f, 0.f, 0.f, 0.f};
        f32x4 a1 = (f32x4){0.f, 0.f, 0.f, 0.f};
#pragma unroll
        for (int ks = 0; ks < 2; ++ks) {
          a0 = MFMA(xah[ks], wh[cb][0][ks], a0);
          a1 = MFMA(xah[ks], wh[cb][1][ks], a1);
          a0 = MFMA(xal[ks], wh[cb][0][ks], a0);
          a1 = MFMA(xal[ks], wh[cb][1][ks], a1);
          a0 = MFMA(xah[ks], wl[cb][0][ks], a0);
          a1 = MFMA(xah[ks], wl[cb][1][ks], a1);
        }
        const int j0 = (pr * 2) * 16 + nl, j1 = (pr * 2 + 1) * 16 + nl;
#pragma unroll
        for (int r = 0; r < 4; ++r) {
          qkvb[(quad * 4 + r) * 196 + j0] = a0[r] + qb[pr * 2];
          qkvb[(quad * 4 + r) * 196 + j1] = a1[r] + qb[pr * 2 + 1];
        }
      }
    }

    // ---- preload proj weights + biases + LN1 params (hide under attn) ----
    bf16x8 pwh[2][2][2], pwl[2][2][2];
#pragma unroll
    for (int pp = 0; pp < 2; ++pp)
#pragma unroll
      for (int tp = 0; tp < 2; ++tp)
#pragma unroll
        for (int ks = 0; ks < 2; ++ks) {
          const int nt = pp * 2 + tp;
          pwh[pp][tp][ks] = *(const bf16x8*)(TH + 12288 + (nt * 16 + nl) * 64 + ks * 32 + quad * 8);
          pwl[pp][tp][ks] = *(const bf16x8*)(TL + 12288 + (nt * 16 + nl) * 64 + ks * 32 + quad * 8);
        }
    float pb[4];
#pragma unroll
    for (int nt = 0; nt < 4; ++nt) pb[nt] = bo[l * 64 + nt * 16 + nl];
    float4 g1v4 = ((const float4*)(ln1g + l * 64))[nl];
    float4 b1v4 = ((const float4*)(ln1b + l * 64))[nl];
    // ff1 weights prefetch too (attention ~2k cyc hides them)
    bf16x8 fwh[4][2][2], fwl[4][2][2];
#pragma unroll
    for (int pp = 0; pp < 4; ++pp)
#pragma unroll
      for (int tp = 0; tp < 2; ++tp)
#pragma unroll
        for (int ks = 0; ks < 2; ++ks) {
          const int nt = pp * 2 + tp;
          fwh[pp][tp][ks] = *(const bf16x8*)(TH + 16384 + (nt * 16 + nl) * 64 + ks * 32 + quad * 8);
          fwl[pp][tp][ks] = *(const bf16x8*)(TL + 16384 + (nt * 16 + nl) * 64 + ks * 32 + quad * 8);
        }
    float fb[8];
#pragma unroll
    for (int nt = 0; nt < 8; ++nt) fb[nt] = b1[l * 128 + nt * 16 + nl];

    // ================= attention (intra-wave) =================
#pragma unroll
    for (int h = 0; h < NH_; ++h) {
      float sc[4];
      const float4* qr = (const float4*)(qkvb + nl * 196 + h * 16);
      float4 q0 = qr[0], q1 = qr[1], q2 = qr[2], q3 = qr[3];
#pragma unroll
      for (int uu = 0; uu < 4; ++uu) {
        const float4* kr = (const float4*)(qkvb + (quad * 4 + uu) * 196 + 64 + h * 16);
        float4 k0 = kr[0], k1 = kr[1], k2 = kr[2], k3 = kr[3];
        float a = q0.x * k0.x + q0.y * k0.y + q0.z * k0.z + q0.w * k0.w
                + q1.x * k1.x + q1.y * k1.y + q1.z * k1.z + q1.w * k1.w
                + q2.x * k2.x + q2.y * k2.y + q2.z * k2.z + q2.w * k2.w
                + q3.x * k3.x + q3.y * k3.y + q3.z * k3.z + q3.w * k3.w;
        sc[uu] = a * 0.25f;
      }
      float mx = fmaxf(fmaxf(sc[0], sc[1]), fmaxf(sc[2], sc[3]));
      mx = fmaxf(mx, __shfl_xor(mx, 16));
      mx = fmaxf(mx, __shfl_xor(mx, 32));
      float e[4];
      float sum = 0.f;
#pragma unroll
      for (int uu = 0; uu < 4; ++uu) { e[uu] = expf(sc[uu] - mx); sum += e[uu]; }
      sum += __shfl_xor(sum, 16);
      sum += __shfl_xor(sum, 32);
      const float is = 1.f / sum;
      float* prow = &scb[nl * 17];
#pragma unroll
      for (int uu = 0; uu < 4; ++uu) prow[quad * 4 + uu] = e[uu] * is;
      float o0 = 0.f, o1 = 0.f, o2 = 0.f, o3 = 0.f;
#pragma unroll
      for (int u = 0; u < 16; ++u) {
        float p = prow[u];
        float4 vv = *(const float4*)(qkvb + u * 196 + 128 + h * 16 + quad * 4);
        o0 += p * vv.x; o1 += p * vv.y; o2 += p * vv.z; o3 += p * vv.w;
      }
      const int eb = nl * 72 + h * 16 + quad * 4;
      ushort_t h0 = f2bf(o0), h1 = f2bf(o1), h2 = f2bf(o2), h3 = f2bf(o3);
      oh[eb + 0] = h0; oh[eb + 1] = h1; oh[eb + 2] = h2; oh[eb + 3] = h3;
      ol[eb + 0] = f2bf(o0 - bf2f(h0));
      ol[eb + 1] = f2bf(o1 - bf2f(h1));
      ol[eb + 2] = f2bf(o2 - bf2f(h2));
      ol[eb + 3] = f2bf(o3 - bf2f(h3));
    }

    // ================= proj + residual (weights preloaded) =================
    {
      bf16x8 oah[2], oal[2];
#pragma unroll
      for (int ks = 0; ks < 2; ++ks) {
        oah[ks] = *(const bf16x8*)(oh + nl * 72 + ks * 32 + quad * 8);
        oal[ks] = *(const bf16x8*)(ol + nl * 72 + ks * 32 + quad * 8);
      }
#pragma unroll
      for (int pp = 0; pp < 2; ++pp) {
        f32x4 a0 = (f32x4){0.f, 0.f, 0.f, 0.f};
        f32x4 a1 = (f32x4){0.f, 0.f, 0.f, 0.f};
#pragma unroll
        for (int ks = 0; ks < 2; ++ks) {
          a0 = MFMA(oah[ks], pwh[pp][0][ks], a0);
          a1 = MFMA(oah[ks], pwh[pp][1][ks], a1);
          a0 = MFMA(oal[ks], pwh[pp][0][ks], a0);
          a1 = MFMA(oal[ks], pwh[pp][1][ks], a1);
          a0 = MFMA(oah[ks], pwl[pp][0][ks], a0);
          a1 = MFMA(oah[ks], pwl[pp][1][ks], a1);
        }
        const int d0 = (pp * 2) * 16 + nl, d1 = (pp * 2 + 1) * 16 + nl;
#pragma unroll
        for (int r = 0; r < 4; ++r) {
          int t = quad * 4 + r;
          tmpb[t * 64 + d0] = xbuf[t * 64 + d0] + a0[r] + pb[pp * 2];
          tmpb[t * 64 + d1] = xbuf[t * 64 + d1] + a1[r] + pb[pp * 2 + 1];
        }
      }
    }

    // ---- preload ff2 weights + b2 + LN2 params (hide under LN1+ff1) ----
    bf16x8 gwh[2][2][4], gwl[2][2][4];
#pragma unroll
    for (int pp = 0; pp < 2; ++pp)
#pragma unroll
      for (int tp = 0; tp < 2; ++tp)
#pragma unroll
        for (int ks = 0; ks < 4; ++ks) {
          const int nt = pp * 2 + tp;
          gwh[pp][tp][ks] = *(const bf16x8*)(TH + 24576 + (nt * 16 + nl) * 128 + ks * 32 + quad * 8);
          gwl[pp][tp][ks] = *(const bf16x8*)(TL + 24576 + (nt * 16 + nl) * 128 + ks * 32 + quad * 8);
        }
    float gb[4];
#pragma unroll
    for (int nt = 0; nt < 4; ++nt) gb[nt] = b2[l * 64 + nt * 16 + nl];
    float4 g2v4 = ((const float4*)(ln2g + l * 64))[nl];
    float4 b2v4 = ((const float4*)(ln2b + l * 64))[nl];

    // ================= LN1 =================
#pragma unroll
    for (int g = 0; g < 4; ++g) {
      const int t = g * 4 + quad;
      float4 v = ((const float4*)(tmpb + t * 64))[nl];
      float s = v.x + v.y + v.z + v.w;
      s += __shfl_xor(s, 1); s += __shfl_xor(s, 2);
      s += __shfl_xor(s, 4); s += __shfl_xor(s, 8);
      float mu = s * (1.f / 64.f);
      float d0 = v.x - mu, d1 = v.y - mu, d2 = v.z - mu, d3 = v.w - mu;
      float vr = d0 * d0 + d1 * d1 + d2 * d2 + d3 * d3;
      vr += __shfl_xor(vr, 1); vr += __shfl_xor(vr, 2);
      vr += __shfl_xor(vr, 4); vr += __shfl_xor(vr, 8);
      float rs = rsqrtf(vr * (1.f / 64.f) + EPS_);
      float4 o4;
      o4.x = d0 * rs * g1v4.x + b1v4.x; o4.y = d1 * rs * g1v4.y + b1v4.y;
      o4.z = d2 * rs * g1v4.z + b1v4.z; o4.w = d3 * rs * g1v4.w + b1v4.w;
      ((float4*)(xbuf + t * 64))[nl] = o4;
      const int bi = t * 72 + nl * 4;
      ushort_t h0 = f2bf(o4.x), h1 = f2bf(o4.y), h2 = f2bf(o4.z), h3 = f2bf(o4.w);
      xh[bi + 0] = h0; xh[bi + 1] = h1; xh[bi + 2] = h2; xh[bi + 3] = h3;
      xl[bi + 0] = f2bf(o4.x - bf2f(h0));
      xl[bi + 1] = f2bf(o4.y - bf2f(h1));
      xl[bi + 2] = f2bf(o4.z - bf2f(h2));
      xl[bi + 3] = f2bf(o4.w - bf2f(h3));
    }

    // ================= ff1 (weights preloaded) =================
    {
      bf16x8 xah[2], xal[2];
#pragma unroll
      for (int ks = 0; ks < 2; ++ks) {
        xah[ks] = *(const bf16x8*)(xh + nl * 72 + ks * 32 + quad * 8);
        xal[ks] = *(const bf16x8*)(xl + nl * 72 + ks * 32 + quad * 8);
      }
#pragma unroll
      for (int pp = 0; pp < 4; ++pp) {
        f32x4 a0 = (f32x4){0.f, 0.f, 0.f, 0.f};
        f32x4 a1 = (f32x4){0.f, 0.f, 0.f, 0.f};
#pragma unroll
        for (int ks = 0; ks < 2; ++ks) {
          a0 = MFMA(xah[ks], fwh[pp][0][ks], a0);
          a1 = MFMA(xah[ks], fwh[pp][1][ks], a1);
          a0 = MFMA(xal[ks], fwh[pp][0][ks], a0);
          a1 = MFMA(xal[ks], fwh[pp][1][ks], a1);
          a0 = MFMA(xah[ks], fwl[pp][0][ks], a0);
          a1 = MFMA(xah[ks], fwl[pp][1][ks], a1);
        }
        const int f0 = (pp * 2) * 16 + nl, f1 = (pp * 2 + 1) * 16 + nl;
#pragma unroll
        for (int r = 0; r < 4; ++r) {
          int t = quad * 4 + r;
          float v0 = fmaxf(a0[r] + fb[pp * 2], 0.f);
          float v1 = fmaxf(a1[r] + fb[pp * 2 + 1], 0.f);
          ushort_t hh0 = f2bf(v0), hh1 = f2bf(v1);
          h1h[t * 136 + f0] = hh0;
          h1l[t * 136 + f0] = f2bf(v0 - bf2f(hh0));
          h1h[t * 136 + f1] = hh1;
          h1l[t * 136 + f1] = f2bf(v1 - bf2f(hh1));
        }
      }
    }

    // ================= ff2 + residual (weights preloaded) =================
    {
      bf16x8 hah[4], hal[4];
#pragma unroll
      for (int ks = 0; ks < 4; ++ks) {
        hah[ks] = *(const bf16x8*)(h1h + nl * 136 + ks * 32 + quad * 8);
        hal[ks] = *(const bf16x8*)(h1l + nl * 136 + ks * 32 + quad * 8);
      }
#pragma unroll
      for (int pp = 0; pp < 2; ++pp) {
        f32x4 a0 = (f32x4){0.f, 0.f, 0.f, 0.f};
        f32x4 a1 = (f32x4){0.f, 0.f, 0.f, 0.f};
#pragma unroll
        for (int ks = 0; ks < 4; ++ks) {
          a0 = MFMA(hah[ks], gwh[pp][0][ks], a0);
          a1 = MFMA(hah[ks], gwh[pp][1][ks], a1);
          a0 = MFMA(hal[ks], gwh[pp][0][ks], a0);
          a1 = MFMA(hal[ks], gwh[pp][1][ks], a1);
          a0 = MFMA(hah[ks], gwl[pp][0][ks], a0);
          a1 = MFMA(hah[ks], gwl[pp][1][ks], a1);
        }
        const int d0 = (pp * 2) * 16 + nl, d1 = (pp * 2 + 1) * 16 + nl;
#pragma unroll
        for (int r = 0; r < 4; ++r) {
          int t = quad * 4 + r;
          tmpb[t * 64 + d0] = xbuf[t * 64 + d0] + a0[r] + gb[pp * 2];
          tmpb[t * 64 + d1] = xbuf[t * 64 + d1] + a1[r] + gb[pp * 2 + 1];
        }
      }
    }

    // ================= LN2 =================
#pragma unroll
    for (int g = 0; g < 4; ++g) {
      const int t = g * 4 + quad;
      float4 v = ((const float4*)(tmpb + t * 64))[nl];
      float s = v.x + v.y + v.z + v.w;
      s += __shfl_xor(s, 1); s += __shfl_xor(s, 2);
      s += __shfl_xor(s, 4); s += __shfl_xor(s, 8);
      float mu = s * (1.f / 64.f);
      float d0 = v.x - mu, d1 = v.y - mu, d2 = v.z - mu, d3 = v.w - mu;
      float vr = d0 * d0 + d1 * d1 + d2 * d2 + d3 * d3;
      vr += __shfl_xor(vr, 1); vr += __shfl_xor(vr, 2);
      vr += __shfl_xor(vr, 4); vr += __shfl_xor(vr, 8);
      float rs = rsqrtf(vr * (1.f / 64.f) + EPS_);
      float4 o4;
      o4.x = d0 * rs * g2v4.x + b2v4.x; o4.y = d1 * rs * g2v4.y + b2v4.y;
      o4.z = d2 * rs * g2v4.z + b2v4.z; o4.w = d3 * rs * g2v4.w + b2v4.w;
      ((float4*)(xbuf + t * 64))[nl] = o4;
      const int bi = t * 72 + nl * 4;
      ushort_t h0 = f2bf(o4.x), h1 = f2bf(o4.y), h2 = f2bf(o4.z), h3 = f2bf(o4.w);
      xh[bi + 0] = h0; xh[bi + 1] = h1; xh[bi + 2] = h2; xh[bi + 3] = h3;
      xl[bi + 0] = f2bf(o4.x - bf2f(h0));
      xl[bi + 1] = f2bf(o4.y - bf2f(h1));
      xl[bi + 2] = f2bf(o4.z - bf2f(h2));
      xl[bi + 3] = f2bf(o4.w - bf2f(h3));
    }
  }

  // ---- classifier on cls token ----
  if (lane < NC_) {
    float acc = clfb[lane];
    const float* wr = &clfw[lane * DM_];
    for (int d = 0; d < DM_; ++d) acc += xbuf[d] * wr[d];
    out[b * NC_ + lane] = acc;
  }
}

extern "C" void kernel_launch(void* const* d_in, const int* in_sizes, int n_in,
                              void* d_out, int out_size, void* d_ws, size_t ws_size,
                              hipStream_t stream) {
  (void)in_sizes; (void)n_in; (void)out_size; (void)ws_size;
  const float* X    = (const float*)d_in[0];
  const float* A    = (const float*)d_in[1];
  const float* c1w  = (const float*)d_in[2];
  const float* c1b  = (const float*)d_in[3];
  const float* c2w  = (const float*)d_in[4];
  const float* c2b  = (const float*)d_in[5];
  const float* g1W  = (const float*)d_in[6];
  const float* g1q  = (const float*)d_in[7];
  const float* g1g  = (const float*)d_in[8];
  const float* g1b  = (const float*)d_in[9];
  const float* g1m  = (const float*)d_in[10];
  const float* g1v  = (const float*)d_in[11];
  const float* g2W  = (const float*)d_in[12];
  const float* g2q  = (const float*)d_in[13];
  const float* g2g  = (const float*)d_in[14];
  const float* g2b  = (const float*)d_in[15];
  const float* g2m  = (const float*)d_in[16];
  const float* g2v  = (const float*)d_in[17];
  const float* cls  = (const float*)d_in[18];
  const float* pos  = (const float*)d_in[19];
  const float* wqkv = (const float*)d_in[20];
  const float* bqkv = (const float*)d_in[21];
  const float* wo   = (const float*)d_in[22];
  const float* bo   = (const float*)d_in[23];
  const float* ln1g = (const float*)d_in[24];
  const float* ln1b = (const float*)d_in[25];
  const float* w1   = (const float*)d_in[26];
  const float* b1   = (const float*)d_in[27];
  const float* w2   = (const float*)d_in[28];
  const float* b2   = (const float*)d_in[29];
  const float* ln2g = (const float*)d_in[30];
  const float* ln2b = (const float*)d_in[31];
  const float* clfw = (const float*)d_in[32];
  const float* clfb = (const float*)d_in[33];
  float* out = (float*)d_out;

  // ---- workspace layout (bytes) ----
  char* wsb = (char*)d_ws;
  ushort_t* BmatT = (ushort_t*)(wsb + 0);                  //  37888
  ushort_t* Th  = (ushort_t*)(wsb + 37888);                // 262144
  ushort_t* Tl  = (ushort_t*)(wsb + 300032);               // 262144
  ushort_t* W1h = (ushort_t*)(wsb + 562176);               //  16384
  ushort_t* W1l = (ushort_t*)(wsb + 578560);               //  16384
  ushort_t* W2h = (ushort_t*)(wsb + 594944);               //  16384
  ushort_t* W2l = (ushort_t*)(wsb + 611328);               //  16384
  ushort_t* C1h = (ushort_t*)(wsb + 627712);               //   2048
  ushort_t* C1l = (ushort_t*)(wsb + 629760);               //   2048
  float* Xf   = (float*)(wsb + 631808);                    // 4669440
  float* G    = (float*)(wsb + 5301248);                   //  245760

  k_prep<<<654, 256, 0, stream>>>(c1w, c2w, wqkv, wo, w1, w2, g1W, g2W,
                                  BmatT, Th, Tl, W1h, W1l, W2h, W2l, C1h, C1l);
  k_temporal<<<B_ * SEG_ * N_ / RPB, 256, 0, stream>>>(
      X, c1b, c2b, C1h, C1l, BmatT, Xf);
  k_gcn<<<B_ * SEG_, 256, 0, stream>>>(A, Xf, W1h, W1l, W2h, W2l,
                                       g1q, g2q, g1g, g1b, g1m, g1v,
                                       g2g, g2b, g2m, g2v, G);
  k_transformer<<<B_, 64, 0, stream>>>(G, cls, pos, Th, Tl,
                                       bqkv, bo, ln1g, ln1b, b1, b2, ln2g, ln2b,
                                       clfw, clfb, out);
}

// Round 11
// 219.564 us; speedup vs baseline: 1.1450x; 1.1450x over previous
//
#include <hip/hip_runtime.h>
#include <cmath>

#define B_ 64
#define N_ 19
#define SEG_ 15
#define T_ 400
#define FIN_ 64
#define HID_ 128
#define K_ 4
#define NH_ 4
#define DM_ 64
#define FF_ 128
#define L_ 4
#define NC_ 3
#define EPS_ 1e-5f

typedef __attribute__((ext_vector_type(8))) short bf16x8;
typedef __attribute__((ext_vector_type(4))) short bf16x4;
typedef __attribute__((ext_vector_type(4))) float f32x4;
typedef unsigned short ushort_t;

__device__ __forceinline__ ushort_t f2bf(float x) {
  union { float f; unsigned u; } a; a.f = x;
  unsigned r = a.u + 0x7fffu + ((a.u >> 16) & 1u);
  return (ushort_t)(r >> 16);
}
__device__ __forceinline__ float bf2f(ushort_t h) {
  union { unsigned u; float f; } a; a.u = ((unsigned)h) << 16;
  return a.f;
}
#define MFMA(a, b, c) __builtin_amdgcn_mfma_f32_16x16x32_bf16((a), (b), (c), 0, 0, 0)

// ================= k_prep =================
__global__ __launch_bounds__(256) void k_prep(
    const float* __restrict__ c1w, const float* __restrict__ c2w,
    const float* __restrict__ wqkv, const float* __restrict__ wo,
    const float* __restrict__ w1, const float* __restrict__ w2,
    const float* __restrict__ g1W, const float* __restrict__ g2W,
    ushort_t* __restrict__ bt,
    ushort_t* __restrict__ Th, ushort_t* __restrict__ Tl,
    ushort_t* __restrict__ W1h, ushort_t* __restrict__ W1l,
    ushort_t* __restrict__ W2h, ushort_t* __restrict__ W2l,
    ushort_t* __restrict__ C1h, ushort_t* __restrict__ C1l) {
  int gid = blockIdx.x * 256 + threadIdx.x;
  if (gid < 18944) {
    int oc = gid / 296, k = gid - oc * 296;
    int ic = k & 31, kk = k >> 5;
    ushort_t v = 0;
    if (kk < 9) v = f2bf(c2w[oc * 288 + ic * 9 + kk]);
    bt[gid] = v;
  } else if (gid < 68096) {
    int i = gid - 18944;
    int l = i / 12288, r = i % 12288;
    float v = wqkv[i];
    ushort_t h = f2bf(v);
    int dst = l * 32768 + r;
    Th[dst] = h; Tl[dst] = f2bf(v - bf2f(h));
  } else if (gid < 84480) {
    int i = gid - 68096;
    int l = i / 4096, r = i % 4096;
    float v = wo[i];
    ushort_t h = f2bf(v);
    int dst = l * 32768 + 12288 + r;
    Th[dst] = h; Tl[dst] = f2bf(v - bf2f(h));
  } else if (gid < 117248) {
    int i = gid - 84480;
    int l = i / 8192, r = i % 8192;
    float v = w1[i];
    ushort_t h = f2bf(v);
    int dst = l * 32768 + 16384 + r;
    Th[dst] = h; Tl[dst] = f2bf(v - bf2f(h));
  } else if (gid < 150016) {
    int i = gid - 117248;
    int l = i / 8192, r = i % 8192;
    float v = w2[i];
    ushort_t h = f2bf(v);
    int dst = l * 32768 + 24576 + r;
    Th[dst] = h; Tl[dst] = f2bf(v - bf2f(h));
  } else if (gid < 158208) {
    int i = gid - 150016;
    float v = g1W[i];
    ushort_t h = f2bf(v);
    W1h[i] = h;
    W1l[i] = f2bf(v - bf2f(h));
  } else if (gid < 166400) {
    int i = gid - 158208;
    float v = g2W[i];
    ushort_t h = f2bf(v);
    W2h[i] = h;
    W2l[i] = f2bf(v - bf2f(h));
  } else if (gid < 167424) {
    int i = gid - 166400;
    int oc = i >> 5, kk = i & 31;
    float v = (kk < 25) ? c1w[oc * 25 + kk] : 0.f;
    ushort_t h = f2bf(v);
    C1h[i] = h;
    C1l[i] = f2bf(v - bf2f(h));
  }
}

// ================= Kernel 1: temporal encoder (bounds 256,5) ==========
#define RPB 4
#define ICP 40
#define P1R 40
#define OFF_XPH 0
#define OFF_XPL 3840
#define OFF_P1  7680
#define SMEM_T  20480

__global__ __launch_bounds__(256, 5) void k_temporal(
    const float* __restrict__ X, const float* __restrict__ c1b,
    const float* __restrict__ c2b,
    const ushort_t* __restrict__ C1h, const ushort_t* __restrict__ C1l,
    const ushort_t* __restrict__ BmatT, float* __restrict__ Xf) {
  __shared__ __align__(16) unsigned char smem[SMEM_T];
  ushort_t* xph = (ushort_t*)(smem + OFF_XPH);
  ushort_t* xpl = (ushort_t*)(smem + OFF_XPL);
  ushort_t* p1T = (ushort_t*)(smem + OFF_P1);
  float* Dbuf = (float*)smem;

  const int tid = threadIdx.x;
  const int row0 = blockIdx.x * RPB;
  const int lane = tid & 63, wv = tid >> 6;
  const int quad = lane >> 4, nl = lane & 15;

  for (int i = tid; i < 3200; i += 256) ((unsigned*)p1T)[i] = 0u;
  for (int r = 0; r < RPB; ++r) {
    const int gr = row0 + r;
    const int n = gr % N_;
    const int s = (gr / N_) % SEG_;
    const int b = gr / (N_ * SEG_);
    const float* xin = X + (((size_t)b * N_ + n) * SEG_ + s) * T_ - 12;
    for (int i = tid; i < 480; i += 256) {
      float v = (i >= 12 && i < 412) ? xin[i] : 0.f;
      ushort_t h = f2bf(v);
      xph[r * 480 + i] = h;
      xpl[r * 480 + i] = f2bf(v - bf2f(h));
    }
  }
  __syncthreads();

  {
    bf16x8 bh0 = *(const bf16x8*)(C1h + nl * 32 + quad * 8);
    bf16x8 bh1 = *(const bf16x8*)(C1h + (16 + nl) * 32 + quad * 8);
    bf16x8 bl0 = *(const bf16x8*)(C1l + nl * 32 + quad * 8);
    bf16x8 bl1 = *(const bf16x8*)(C1l + (16 + nl) * 32 + quad * 8);
    const float bias0 = c1b[nl], bias1 = c1b[16 + nl];
    for (int t = wv; t < 28; t += 4) {
      const int r = t / 7, mt = t - r * 7;
      const int aoff = r * 480 + mt * 64 + nl * 4 + quad * 8;
      union { bf16x4 q[2]; bf16x8 v; } ah, al;
      ah.q[0] = *(const bf16x4*)(xph + aoff);
      ah.q[1] = *(const bf16x4*)(xph + aoff + 4);
      al.q[0] = *(const bf16x4*)(xpl + aoff);
      al.q[1] = *(const bf16x4*)(xpl + aoff + 4);
      f32x4 a0 = (f32x4){0.f, 0.f, 0.f, 0.f};
      a0 = MFMA(ah.v, bh0, a0);
      a0 = MFMA(al.v, bh0, a0);
      a0 = MFMA(ah.v, bl0, a0);
      f32x4 a1 = (f32x4){0.f, 0.f, 0.f, 0.f};
      a1 = MFMA(ah.v, bh1, a1);
      a1 = MFMA(al.v, bh1, a1);
      a1 = MFMA(ah.v, bl1, a1);
      const int j = mt * 4 + quad;
      if (j < 25) {
        float m0 = fmaxf(fmaxf(a0[0], a0[1]), fmaxf(a0[2], a0[3]));
        float m1 = fmaxf(fmaxf(a1[0], a1[1]), fmaxf(a1[2], a1[3]));
        p1T[(r * P1R + j + 4) * ICP + nl] = f2bf(fmaxf(m0 + bias0, 0.f));
        p1T[(r * P1R + j + 4) * ICP + 16 + nl] = f2bf(fmaxf(m1 + bias1, 0.f));
      }
    }
  }
  __syncthreads();

  f32x4 acc[4];
  int abase[4];
#pragma unroll
  for (int tm = 0; tm < 4; ++tm) {
    acc[tm] = (f32x4){0.f, 0.f, 0.f, 0.f};
    int m = tm * 16 + nl;
    int rl = m / 14;
    int op = m - rl * 14;
    if (rl > 3) rl = 3;
    if (op > 13) op = 13;
    abase[tm] = (rl * P1R + 2 * op) * ICP + quad * 8;
  }
  const ushort_t* brow = BmatT + (wv * 16 + nl) * 296 + quad * 8;
#pragma unroll
  for (int kk = 0; kk < 9; ++kk) {
    bf16x8 bfr = *(const bf16x8*)(brow + kk * 32);
#pragma unroll
    for (int tm = 0; tm < 4; ++tm) {
      bf16x8 afr = *(const bf16x8*)(p1T + abase[tm] + kk * ICP);
      acc[tm] = MFMA(afr, bfr, acc[tm]);
    }
  }
  __syncthreads();

#pragma unroll
  for (int tm = 0; tm < 4; ++tm)
#pragma unroll
    for (int rg = 0; rg < 4; ++rg)
      Dbuf[(tm * 16 + quad * 4 + rg) * 66 + wv * 16 + nl] = acc[tm][rg];
  __syncthreads();

  for (int o = tid; o < RPB * 64; o += 256) {
    int rl = o >> 6, oc = o & 63;
    float bias = c2b[oc];
    const float* dr = Dbuf + (rl * 14) * 66 + oc;
    float s = 0.f;
#pragma unroll
    for (int jj = 0; jj < 6; ++jj) {
      float v = fmaxf(dr[(2 * jj) * 66], dr[(2 * jj + 1) * 66]) + bias;
      s += fmaxf(v, 0.f);
    }
    Xf[(size_t)(row0 + rl) * FIN_ + oc] = s * (1.f / 6.f);
  }
}

// ================= Kernel 2: fused GCN, all-MFMA (unchanged) =============
__global__ __launch_bounds__(256, 2) void k_gcn(
    const float* __restrict__ A, const float* __restrict__ Xf,
    const ushort_t* __restrict__ W1h, const ushort_t* __restrict__ W1l,
    const ushort_t* __restrict__ W2h, const ushort_t* __restrict__ W2l,
    const float* __restrict__ q1, const float* __restrict__ q2,
    const float* __restrict__ b1g, const float* __restrict__ b1b,
    const float* __restrict__ b1m, const float* __restrict__ b1v,
    const float* __restrict__ b2g, const float* __restrict__ b2b,
    const float* __restrict__ b2m, const float* __restrict__ b2v,
    float* __restrict__ G) {
  const int bs = blockIdx.x;
  const int b = bs / SEG_;
  const int s = bs % SEG_;
  const int tid = threadIdx.x;
  const int lane = tid & 63, wv = tid >> 6;
  const int quad = lane >> 4, nl = lane & 15;

  __shared__ __align__(16) ushort_t xh[32 * 72], xl[32 * 72];
  __shared__ __align__(16) ushort_t Hh[32 * 136], Hl[32 * 136];
  __shared__ __align__(16) ushort_t a1h[32 * 40], a1l[32 * 40];
  __shared__ __align__(16) ushort_t a2h[32 * 40], a2l[32 * 40];
  __shared__ __align__(16) ushort_t yTh[128 * 40], yTl[128 * 40];
  __shared__ float zbuf[N_ * 64];
  __shared__ float sc1[HID_], sh1[HID_], sc2[FIN_], sh2[FIN_];

  for (int i = tid; i < 32 * 72 / 2; i += 256) {
    ((unsigned*)xh)[i] = 0u; ((unsigned*)xl)[i] = 0u;
  }
  for (int i = tid; i < 32 * 136 / 2; i += 256) {
    ((unsigned*)Hh)[i] = 0u; ((unsigned*)Hl)[i] = 0u;
  }
  for (int i = tid; i < 32 * 40 / 2; i += 256) {
    ((unsigned*)a1h)[i] = 0u; ((unsigned*)a1l)[i] = 0u;
    ((unsigned*)a2h)[i] = 0u; ((unsigned*)a2l)[i] = 0u;
  }
  for (int o = tid; o < HID_; o += 256) {
    float sc = b1g[o] * rsqrtf(b1v[o] + EPS_);
    sc1[o] = sc; sh1[o] = b1b[o] - b1m[o] * sc;
  }
  for (int o = tid; o < FIN_; o += 256) {
    float sc = b2g[o] * rsqrtf(b2v[o] + EPS_);
    sc2[o] = sc; sh2[o] = b2b[o] - b2m[o] * sc;
  }
  __syncthreads();

  {
    float p0 = q1[0], p1 = q1[1], p2 = q1[2], p3 = q1[3];
    float mx = fmaxf(fmaxf(p0, p1), fmaxf(p2, p3));
    float e0 = expf(p0 - mx), e1 = expf(p1 - mx), e2 = expf(p2 - mx), e3 = expf(p3 - mx);
    float inv = 1.f / (e0 + e1 + e2 + e3);
    float a0 = e0 * inv, a1 = e1 * inv, a2 = e2 * inv, a3 = e3 * inv;
    float r0 = q2[0], r1 = q2[1], r2 = q2[2], r3 = q2[3];
    float mx2 = fmaxf(fmaxf(r0, r1), fmaxf(r2, r3));
    float f0 = expf(r0 - mx2), f1 = expf(r1 - mx2), f2 = expf(r2 - mx2), f3 = expf(r3 - mx2);
    float inv2 = 1.f / (f0 + f1 + f2 + f3);
    float c0 = f0 * inv2, c1 = f1 * inv2, c2 = f2 * inv2, c3 = f3 * inv2;
    const size_t kstride = (size_t)SEG_ * N_ * N_;
    const float* Ab = A + ((size_t)b * K_ * SEG_ + s) * (N_ * N_);
    for (int i = tid; i < N_ * N_; i += 256) {
      int n = i / N_, m = i - n * N_;
      float v0 = Ab[i], v1 = Ab[i + kstride], v2 = Ab[i + 2 * kstride], v3 = Ab[i + 3 * kstride];
      float w1v = a0 * v0 + a1 * v1 + a2 * v2 + a3 * v3;
      float w2v = c0 * v0 + c1 * v1 + c2 * v2 + c3 * v3;
      ushort_t h1 = f2bf(w1v);
      a1h[n * 40 + m] = h1; a1l[n * 40 + m] = f2bf(w1v - bf2f(h1));
      ushort_t h2 = f2bf(w2v);
      a2h[n * 40 + m] = h2; a2l[n * 40 + m] = f2bf(w2v - bf2f(h2));
    }
  }
  {
    const float* xb = Xf + (size_t)bs * N_ * FIN_;
    for (int i = tid; i < N_ * FIN_; i += 256) {
      int r = i >> 6, f = i & 63;
      float v = xb[i];
      ushort_t h = f2bf(v);
      xh[r * 72 + f] = h;
      xl[r * 72 + f] = f2bf(v - bf2f(h));
    }
  }
  __syncthreads();

#pragma unroll
  for (int mtl = 0; mtl < 2; ++mtl) {
    const int om = (wv * 2 + mtl) * 16;
#pragma unroll
    for (int nt = 0; nt < 2; ++nt) {
      f32x4 acc = (f32x4){0.f, 0.f, 0.f, 0.f};
#pragma unroll
      for (int ks = 0; ks < 2; ++ks) {
        bf16x8 ah = *(const bf16x8*)(W1h + (om + nl) * 64 + ks * 32 + quad * 8);
        bf16x8 al = *(const bf16x8*)(W1l + (om + nl) * 64 + ks * 32 + quad * 8);
        bf16x8 bh = *(const bf16x8*)(xh + (nt * 16 + nl) * 72 + ks * 32 + quad * 8);
        bf16x8 bl = *(const bf16x8*)(xl + (nt * 16 + nl) * 72 + ks * 32 + quad * 8);
        acc = MFMA(ah, bh, acc);
        acc = MFMA(al, bh, acc);
        acc = MFMA(ah, bl, acc);
      }
#pragma unroll
      for (int r = 0; r < 4; ++r) {
        int o = om + quad * 4 + r, node = nt * 16 + nl;
        float v = acc[r];
        ushort_t hh = f2bf(v);
        yTh[o * 40 + node] = hh;
        yTl[o * 40 + node] = f2bf(v - bf2f(hh));
      }
    }
  }
  __syncthreads();

#pragma unroll
  for (int mt = 0; mt < 2; ++mt) {
#pragma unroll
    for (int ntl = 0; ntl < 2; ++ntl) {
      const int nt = wv * 2 + ntl;
      f32x4 acc = (f32x4){0.f, 0.f, 0.f, 0.f};
      bf16x8 ah = *(const bf16x8*)(a1h + (mt * 16 + nl) * 40 + quad * 8);
      bf16x8 al = *(const bf16x8*)(a1l + (mt * 16 + nl) * 40 + quad * 8);
      bf16x8 bh = *(const bf16x8*)(yTh + (nt * 16 + nl) * 40 + quad * 8);
      bf16x8 bl = *(const bf16x8*)(yTl + (nt * 16 + nl) * 40 + quad * 8);
      acc = MFMA(ah, bh, acc);
      acc = MFMA(al, bh, acc);
      acc = MFMA(ah, bl, acc);
      const int o = nt * 16 + nl;
      const float sc = sc1[o], sh = sh1[o];
#pragma unroll
      for (int r = 0; r < 4; ++r) {
        int node = mt * 16 + quad * 4 + r;
        if (node < N_) {
          float h = fmaxf(acc[r] * sc + sh, 0.f);
          ushort_t hh = f2bf(h);
          Hh[node * 136 + o] = hh;
          Hl[node * 136 + o] = f2bf(h - bf2f(hh));
        }
      }
    }
  }
  __syncthreads();

  {
    const int om = wv * 16;
#pragma unroll
    for (int nt = 0; nt < 2; ++nt) {
      f32x4 acc = (f32x4){0.f, 0.f, 0.f, 0.f};
#pragma unroll
      for (int ks = 0; ks < 4; ++ks) {
        bf16x8 ah = *(const bf16x8*)(W2h + (om + nl) * 128 + ks * 32 + quad * 8);
        bf16x8 al = *(const bf16x8*)(W2l + (om + nl) * 128 + ks * 32 + quad * 8);
        bf16x8 bh = *(const bf16x8*)(Hh + (nt * 16 + nl) * 136 + ks * 32 + quad * 8);
        bf16x8 bl = *(const bf16x8*)(Hl + (nt * 16 + nl) * 136 + ks * 32 + quad * 8);
        acc = MFMA(ah, bh, acc);
        acc = MFMA(al, bh, acc);
        acc = MFMA(ah, bl, acc);
      }
#pragma unroll
      for (int r = 0; r < 4; ++r) {
        int o2 = om + quad * 4 + r, node = nt * 16 + nl;
        float v = acc[r];
        ushort_t hh = f2bf(v);
        yTh[o2 * 40 + node] = hh;
        yTl[o2 * 40 + node] = f2bf(v - bf2f(hh));
      }
    }
  }
  __syncthreads();

#pragma unroll
  for (int mt = 0; mt < 2; ++mt) {
    f32x4 acc = (f32x4){0.f, 0.f, 0.f, 0.f};
    bf16x8 ah = *(const bf16x8*)(a2h + (mt * 16 + nl) * 40 + quad * 8);
    bf16x8 al = *(const bf16x8*)(a2l + (mt * 16 + nl) * 40 + quad * 8);
    bf16x8 bh = *(const bf16x8*)(yTh + (wv * 16 + nl) * 40 + quad * 8);
    bf16x8 bl = *(const bf16x8*)(yTl + (wv * 16 + nl) * 40 + quad * 8);
    acc = MFMA(ah, bh, acc);
    acc = MFMA(al, bh, acc);
    acc = MFMA(ah, bl, acc);
    const int o2 = wv * 16 + nl;
    const float sc = sc2[o2], sh = sh2[o2];
#pragma unroll
    for (int r = 0; r < 4; ++r) {
      int node = mt * 16 + quad * 4 + r;
      if (node < N_)
        zbuf[node * 64 + o2] = fmaxf(acc[r] * sc + sh, 0.f);
    }
  }
  __syncthreads();

  if (tid < FIN_) {
    float ssum = 0.f;
#pragma unroll
    for (int nn = 0; nn < N_; ++nn) ssum += zbuf[nn * 64 + tid];
    G[(size_t)bs * FIN_ + tid] = ssum * (1.f / (float)N_);
  }
}

// ================= Kernel 3: transformer (R6 best-known version) ==========
// 4 waves; per-layer register prefetch of weight B-frags; direct bias loads.
__global__ __launch_bounds__(256, 1) void k_transformer(
    const float* __restrict__ G, const float* __restrict__ cls,
    const float* __restrict__ pos,
    const ushort_t* __restrict__ Th, const ushort_t* __restrict__ Tl,
    const float* __restrict__ bqkv, const float* __restrict__ bo,
    const float* __restrict__ ln1g, const float* __restrict__ ln1b,
    const float* __restrict__ b1, const float* __restrict__ b2,
    const float* __restrict__ ln2g, const float* __restrict__ ln2b,
    const float* __restrict__ clfw, const float* __restrict__ clfb,
    float* __restrict__ out) {
  const int b = blockIdx.x;
  const int tid = threadIdx.x;
  const int lane = tid & 63, wv = tid >> 6;
  const int quad = lane >> 4, nl = lane & 15;

  __shared__ float xbuf[16 * 64];
  __shared__ __align__(16) ushort_t xh[16 * 72], xl[16 * 72];
  __shared__ float qkvb[16 * 196];
  __shared__ float scb[NH_ * 272];          // [h][t*17 + u]
  __shared__ __align__(16) ushort_t oh[16 * 72], ol[16 * 72];
  __shared__ __align__(16) ushort_t h1h[16 * 136], h1l[16 * 136];
  __shared__ float tmpb[16 * 64];

  for (int i = tid; i < 16 * 64; i += 256) {
    int t = i >> 6, d = i & 63;
    float base = (t == 0) ? cls[d] : G[((size_t)b * SEG_ + (t - 1)) * DM_ + d];
    float v = base + pos[t * DM_ + d];
    xbuf[i] = v;
    ushort_t h = f2bf(v);
    xh[t * 72 + d] = h;
    xl[t * 72 + d] = f2bf(v - bf2f(h));
  }
  __syncthreads();

  for (int l = 0; l < L_; ++l) {
    const ushort_t* TH = Th + l * 32768;
    const ushort_t* TL = Tl + l * 32768;

    // ---- register-prefetch ALL weight fragments for this layer ----
    bf16x8 qwh[3][2], qwl[3][2];
#pragma unroll
    for (int ntl = 0; ntl < 3; ++ntl)
#pragma unroll
      for (int ks = 0; ks < 2; ++ks) {
        const int nt = wv * 3 + ntl;
        qwh[ntl][ks] = *(const bf16x8*)(TH + (nt * 16 + nl) * 64 + ks * 32 + quad * 8);
        qwl[ntl][ks] = *(const bf16x8*)(TL + (nt * 16 + nl) * 64 + ks * 32 + quad * 8);
      }
    bf16x8 owh[2], owl[2];
#pragma unroll
    for (int ks = 0; ks < 2; ++ks) {
      owh[ks] = *(const bf16x8*)(TH + 12288 + (wv * 16 + nl) * 64 + ks * 32 + quad * 8);
      owl[ks] = *(const bf16x8*)(TL + 12288 + (wv * 16 + nl) * 64 + ks * 32 + quad * 8);
    }
    bf16x8 f1h[2][2], f1l[2][2];
#pragma unroll
    for (int ntl = 0; ntl < 2; ++ntl)
#pragma unroll
      for (int ks = 0; ks < 2; ++ks) {
        const int nt = wv * 2 + ntl;
        f1h[ntl][ks] = *(const bf16x8*)(TH + 16384 + (nt * 16 + nl) * 64 + ks * 32 + quad * 8);
        f1l[ntl][ks] = *(const bf16x8*)(TL + 16384 + (nt * 16 + nl) * 64 + ks * 32 + quad * 8);
      }
    bf16x8 f2h[4], f2l[4];
#pragma unroll
    for (int ks = 0; ks < 4; ++ks) {
      f2h[ks] = *(const bf16x8*)(TH + 24576 + (wv * 16 + nl) * 128 + ks * 32 + quad * 8);
      f2l[ks] = *(const bf16x8*)(TL + 24576 + (wv * 16 + nl) * 128 + ks * 32 + quad * 8);
    }

    // ---- qkv ----
#pragma unroll
    for (int ntl = 0; ntl < 3; ++ntl) {
      const int nt = wv * 3 + ntl;
      f32x4 acc = (f32x4){0.f, 0.f, 0.f, 0.f};
#pragma unroll
      for (int ks = 0; ks < 2; ++ks) {
        bf16x8 ah = *(const bf16x8*)(xh + nl * 72 + ks * 32 + quad * 8);
        bf16x8 al = *(const bf16x8*)(xl + nl * 72 + ks * 32 + quad * 8);
        acc = MFMA(ah, qwh[ntl][ks], acc);
        acc = MFMA(al, qwh[ntl][ks], acc);
        acc = MFMA(ah, qwl[ntl][ks], acc);
      }
      const int j = nt * 16 + nl;
      const float bias = bqkv[l * 192 + j];
#pragma unroll
      for (int r = 0; r < 4; ++r)
        qkvb[(quad * 4 + r) * 196 + j] = acc[r] + bias;
    }
    __syncthreads();

    // ---- attention: wave wv owns head wv ----
    {
      const int h = wv;
      float sc[4];
      const float* qr = &qkvb[nl * 196 + h * 16];
#pragma unroll
      for (int uu = 0; uu < 4; ++uu) {
        const float* kr = &qkvb[(quad * 4 + uu) * 196 + 64 + h * 16];
        float a = 0.f;
#pragma unroll
        for (int d = 0; d < 16; ++d) a += qr[d] * kr[d];
        sc[uu] = a * 0.25f;
      }
      float mx = fmaxf(fmaxf(sc[0], sc[1]), fmaxf(sc[2], sc[3]));
      mx = fmaxf(mx, __shfl_xor(mx, 16));
      mx = fmaxf(mx, __shfl_xor(mx, 32));
      float e[4];
      float sum = 0.f;
#pragma unroll
      for (int uu = 0; uu < 4; ++uu) { e[uu] = expf(sc[uu] - mx); sum += e[uu]; }
      sum += __shfl_xor(sum, 16);
      sum += __shfl_xor(sum, 32);
      const float is = 1.f / sum;
      float* prow = &scb[h * 272 + nl * 17];
#pragma unroll
      for (int uu = 0; uu < 4; ++uu) prow[quad * 4 + uu] = e[uu] * is;
      float o[4] = {0.f, 0.f, 0.f, 0.f};
      for (int u = 0; u < 16; ++u) {
        float p = prow[u];
        const float* vr = &qkvb[u * 196 + 128 + h * 16 + quad * 4];
#pragma unroll
        for (int dd = 0; dd < 4; ++dd) o[dd] += p * vr[dd];
      }
      const int eb = h * 16 + quad * 4;
#pragma unroll
      for (int dd = 0; dd < 4; ++dd) {
        ushort_t hh = f2bf(o[dd]);
        oh[nl * 72 + eb + dd] = hh;
        ol[nl * 72 + eb + dd] = f2bf(o[dd] - bf2f(hh));
      }
    }
    __syncthreads();

    // ---- proj + residual ----
    {
      f32x4 acc = (f32x4){0.f, 0.f, 0.f, 0.f};
#pragma unroll
      for (int ks = 0; ks < 2; ++ks) {
        bf16x8 ah = *(const bf16x8*)(oh + nl * 72 + ks * 32 + quad * 8);
        bf16x8 al = *(const bf16x8*)(ol + nl * 72 + ks * 32 + quad * 8);
        acc = MFMA(ah, owh[ks], acc);
        acc = MFMA(al, owh[ks], acc);
        acc = MFMA(ah, owl[ks], acc);
      }
      const int d = wv * 16 + nl;
      const float bias = bo[l * 64 + d];
#pragma unroll
      for (int r = 0; r < 4; ++r) {
        int t = quad * 4 + r;
        tmpb[t * 64 + d] = xbuf[t * 64 + d] + acc[r] + bias;
      }
    }
    __syncthreads();

    // ---- LN1 ----
    {
      int t = tid >> 4, i2 = tid & 15;
      float4 v = ((const float4*)(tmpb + t * 64))[i2];
      float s = v.x + v.y + v.z + v.w;
      s += __shfl_xor(s, 1); s += __shfl_xor(s, 2);
      s += __shfl_xor(s, 4); s += __shfl_xor(s, 8);
      float mu = s * (1.f / 64.f);
      float d0 = v.x - mu, d1 = v.y - mu, d2 = v.z - mu, d3 = v.w - mu;
      float vr = d0 * d0 + d1 * d1 + d2 * d2 + d3 * d3;
      vr += __shfl_xor(vr, 1); vr += __shfl_xor(vr, 2);
      vr += __shfl_xor(vr, 4); vr += __shfl_xor(vr, 8);
      float rs = rsqrtf(vr * (1.f / 64.f) + EPS_);
      float4 g4 = ((const float4*)(ln1g + l * 64))[i2];
      float4 b4 = ((const float4*)(ln1b + l * 64))[i2];
      float4 o4;
      o4.x = d0 * rs * g4.x + b4.x; o4.y = d1 * rs * g4.y + b4.y;
      o4.z = d2 * rs * g4.z + b4.z; o4.w = d3 * rs * g4.w + b4.w;
      ((float4*)(xbuf + t * 64))[i2] = o4;
      int base = t * 72 + i2 * 4;
      ushort_t h0 = f2bf(o4.x), h1 = f2bf(o4.y), h2 = f2bf(o4.z), h3 = f2bf(o4.w);
      xh[base + 0] = h0; xh[base + 1] = h1; xh[base + 2] = h2; xh[base + 3] = h3;
      xl[base + 0] = f2bf(o4.x - bf2f(h0));
      xl[base + 1] = f2bf(o4.y - bf2f(h1));
      xl[base + 2] = f2bf(o4.z - bf2f(h2));
      xl[base + 3] = f2bf(o4.w - bf2f(h3));
    }
    __syncthreads();

    // ---- ff1 ----
#pragma unroll
    for (int ntl = 0; ntl < 2; ++ntl) {
      const int nt = wv * 2 + ntl;
      f32x4 acc = (f32x4){0.f, 0.f, 0.f, 0.f};
#pragma unroll
      for (int ks = 0; ks < 2; ++ks) {
        bf16x8 ah = *(const bf16x8*)(xh + nl * 72 + ks * 32 + quad * 8);
        bf16x8 al = *(const bf16x8*)(xl + nl * 72 + ks * 32 + quad * 8);
        acc = MFMA(ah, f1h[ntl][ks], acc);
        acc = MFMA(al, f1h[ntl][ks], acc);
        acc = MFMA(ah, f1l[ntl][ks], acc);
      }
      const int f = nt * 16 + nl;
      const float bias = b1[l * 128 + f];
#pragma unroll
      for (int r = 0; r < 4; ++r) {
        int t = quad * 4 + r;
        float v = fmaxf(acc[r] + bias, 0.f);
        ushort_t hh = f2bf(v);
        h1h[t * 136 + f] = hh;
        h1l[t * 136 + f] = f2bf(v - bf2f(hh));
      }
    }
    __syncthreads();

    // ---- ff2 + residual ----
    {
      f32x4 acc = (f32x4){0.f, 0.f, 0.f, 0.f};
#pragma unroll
      for (int ks = 0; ks < 4; ++ks) {
        bf16x8 ah = *(const bf16x8*)(h1h + nl * 136 + ks * 32 + quad * 8);
        bf16x8 al = *(const bf16x8*)(h1l + nl * 136 + ks * 32 + quad * 8);
        acc = MFMA(ah, f2h[ks], acc);
        acc = MFMA(al, f2h[ks], acc);
        acc = MFMA(ah, f2l[ks], acc);
      }
      const int d = wv * 16 + nl;
      const float bias = b2[l * 64 + d];
#pragma unroll
      for (int r = 0; r < 4; ++r) {
        int t = quad * 4 + r;
        tmpb[t * 64 + d] = xbuf[t * 64 + d] + acc[r] + bias;
      }
    }
    __syncthreads();

    // ---- LN2 ----
    {
      int t = tid >> 4, i2 = tid & 15;
      float4 v = ((const float4*)(tmpb + t * 64))[i2];
      float s = v.x + v.y + v.z + v.w;
      s += __shfl_xor(s, 1); s += __shfl_xor(s, 2);
      s += __shfl_xor(s, 4); s += __shfl_xor(s, 8);
      float mu = s * (1.f / 64.f);
      float d0 = v.x - mu, d1 = v.y - mu, d2 = v.z - mu, d3 = v.w - mu;
      float vr = d0 * d0 + d1 * d1 + d2 * d2 + d3 * d3;
      vr += __shfl_xor(vr, 1); vr += __shfl_xor(vr, 2);
      vr += __shfl_xor(vr, 4); vr += __shfl_xor(vr, 8);
      float rs = rsqrtf(vr * (1.f / 64.f) + EPS_);
      float4 g4 = ((const float4*)(ln2g + l * 64))[i2];
      float4 b4 = ((const float4*)(ln2b + l * 64))[i2];
      float4 o4;
      o4.x = d0 * rs * g4.x + b4.x; o4.y = d1 * rs * g4.y + b4.y;
      o4.z = d2 * rs * g4.z + b4.z; o4.w = d3 * rs * g4.w + b4.w;
      ((float4*)(xbuf + t * 64))[i2] = o4;
      int base = t * 72 + i2 * 4;
      ushort_t h0 = f2bf(o4.x), h1 = f2bf(o4.y), h2 = f2bf(o4.z), h3 = f2bf(o4.w);
      xh[base + 0] = h0; xh[base + 1] = h1; xh[base + 2] = h2; xh[base + 3] = h3;
      xl[base + 0] = f2bf(o4.x - bf2f(h0));
      xl[base + 1] = f2bf(o4.y - bf2f(h1));
      xl[base + 2] = f2bf(o4.z - bf2f(h2));
      xl[base + 3] = f2bf(o4.w - bf2f(h3));
    }
    __syncthreads();
  }

  if (tid < NC_) {
    float acc = clfb[tid];
    const float* wr = &clfw[tid * DM_];
    for (int d = 0; d < DM_; ++d) acc += xbuf[d] * wr[d];
    out[b * NC_ + tid] = acc;
  }
}

extern "C" void kernel_launch(void* const* d_in, const int* in_sizes, int n_in,
                              void* d_out, int out_size, void* d_ws, size_t ws_size,
                              hipStream_t stream) {
  (void)in_sizes; (void)n_in; (void)out_size; (void)ws_size;
  const float* X    = (const float*)d_in[0];
  const float* A    = (const float*)d_in[1];
  const float* c1w  = (const float*)d_in[2];
  const float* c1b  = (const float*)d_in[3];
  const float* c2w  = (const float*)d_in[4];
  const float* c2b  = (const float*)d_in[5];
  const float* g1W  = (const float*)d_in[6];
  const float* g1q  = (const float*)d_in[7];
  const float* g1g  = (const float*)d_in[8];
  const float* g1b  = (const float*)d_in[9];
  const float* g1m  = (const float*)d_in[10];
  const float* g1v  = (const float*)d_in[11];
  const float* g2W  = (const float*)d_in[12];
  const float* g2q  = (const float*)d_in[13];
  const float* g2g  = (const float*)d_in[14];
  const float* g2b  = (const float*)d_in[15];
  const float* g2m  = (const float*)d_in[16];
  const float* g2v  = (const float*)d_in[17];
  const float* cls  = (const float*)d_in[18];
  const float* pos  = (const float*)d_in[19];
  const float* wqkv = (const float*)d_in[20];
  const float* bqkv = (const float*)d_in[21];
  const float* wo   = (const float*)d_in[22];
  const float* bo   = (const float*)d_in[23];
  const float* ln1g = (const float*)d_in[24];
  const float* ln1b = (const float*)d_in[25];
  const float* w1   = (const float*)d_in[26];
  const float* b1   = (const float*)d_in[27];
  const float* w2   = (const float*)d_in[28];
  const float* b2   = (const float*)d_in[29];
  const float* ln2g = (const float*)d_in[30];
  const float* ln2b = (const float*)d_in[31];
  const float* clfw = (const float*)d_in[32];
  const float* clfb = (const float*)d_in[33];
  float* out = (float*)d_out;

  // ---- workspace layout (bytes) ----
  char* wsb = (char*)d_ws;
  ushort_t* BmatT = (ushort_t*)(wsb + 0);                  //  37888
  ushort_t* Th  = (ushort_t*)(wsb + 37888);                // 262144
  ushort_t* Tl  = (ushort_t*)(wsb + 300032);               // 262144
  ushort_t* W1h = (ushort_t*)(wsb + 562176);               //  16384
  ushort_t* W1l = (ushort_t*)(wsb + 578560);               //  16384
  ushort_t* W2h = (ushort_t*)(wsb + 594944);               //  16384
  ushort_t* W2l = (ushort_t*)(wsb + 611328);               //  16384
  ushort_t* C1h = (ushort_t*)(wsb + 627712);               //   2048
  ushort_t* C1l = (ushort_t*)(wsb + 629760);               //   2048
  float* Xf   = (float*)(wsb + 631808);                    // 4669440
  float* G    = (float*)(wsb + 5301248);                   //  245760

  k_prep<<<654, 256, 0, stream>>>(c1w, c2w, wqkv, wo, w1, w2, g1W, g2W,
                                  BmatT, Th, Tl, W1h, W1l, W2h, W2l, C1h, C1l);
  k_temporal<<<B_ * SEG_ * N_ / RPB, 256, 0, stream>>>(
      X, c1b, c2b, C1h, C1l, BmatT, Xf);
  k_gcn<<<B_ * SEG_, 256, 0, stream>>>(A, Xf, W1h, W1l, W2h, W2l,
                                       g1q, g2q, g1g, g1b, g1m, g1v,
                                       g2g, g2b, g2m, g2v, G);
  k_transformer<<<B_, 256, 0, stream>>>(G, cls, pos, Th, Tl,
                                        bqkv, bo, ln1g, ln1b, b1, b2, ln2g, ln2b,
                                        clfw, clfb, out);
}